// Round 6
// baseline (31891.766 us; speedup 1.0000x reference)
//
#include <hip/hip_runtime.h>
#include <cmath>

// Problem constants
#define Bc   64
#define Sc   512
#define Dc   256
#define Hc   512
#define OUTc 128

// Kernel config
#define NWG  256   // 128 layer0 + 128 layer1 workgroups, all resident (1/CU)
#define NTHR 512   // 8 waves
#define NL0  128
#define JPW  4
#define NROW 16
#define KP   1028  // padded LDS weight row stride

// Flags PACKED (r5's 128B-line spreading was a mistake: 64-lane poll load hit
// 64 distinct MALL lines = 64 requests/inst; packed = 256B contiguous = 2).
#define H1_OFF 1024                 // float offset of h1 buffers (flags in bytes [0,1024))
#define HBUF (Bc * Hc)              // 32768 floats per h buffer
#define H2_OFF (H1_OFF + 2 * HBUF)
#define WS_BYTES ((H2_OFF + 2 * HBUF) * 4)

// ---- coherent accessors: relaxed agent-scope atomics (sc1), no cache flushes ----
__device__ __forceinline__ float2 cload2(const float* p) {
    unsigned long long u = __hip_atomic_load((const unsigned long long*)p,
                                             __ATOMIC_RELAXED, __HIP_MEMORY_SCOPE_AGENT);
    union { unsigned long long u; float2 f; } c; c.u = u; return c.f;
}
__device__ __forceinline__ void cstore1(float* p, float v) {
    union { float f; unsigned u; } c; c.f = v;
    __hip_atomic_store((unsigned*)p, c.u, __ATOMIC_RELAXED, __HIP_MEMORY_SCOPE_AGENT);
}

// per-WG monotonic step flags, packed; ONLY wave 0 of a WG calls this.
// 64 lanes cover 128 flags via two coalesced 256B loads (2 MALL requests each).
__device__ __forceinline__ void wait_layer(const unsigned* flags, unsigned target, int lane) {
    const unsigned* p0 = flags + lane;
    const unsigned* p1 = flags + lane + 64;
    for (;;) {
        unsigned f0 = __hip_atomic_load(p0, __ATOMIC_RELAXED, __HIP_MEMORY_SCOPE_AGENT);
        unsigned f1 = __hip_atomic_load(p1, __ATOMIC_RELAXED, __HIP_MEMORY_SCOPE_AGENT);
        if (__all((f0 >= target) && (f1 >= target))) return;
        __builtin_amdgcn_s_sleep(8);   // ~0.2us detect quantum, low request rate
    }
}

__device__ __forceinline__ float sigmoidf_fast(float v) {
    return 1.0f / (1.0f + __expf(-v));
}

extern "C" __global__ void __launch_bounds__(NTHR)
lstm_persist(const float* __restrict__ x,
             const float* __restrict__ Wih0, const float* __restrict__ Whh0,
             const float* __restrict__ bih0, const float* __restrict__ bhh0,
             const float* __restrict__ Wih1, const float* __restrict__ Whh1,
             const float* __restrict__ bih1, const float* __restrict__ bhh1,
             const float* __restrict__ fcw, const float* __restrict__ fcb,
             float* __restrict__ out, float* __restrict__ wsf)
{
    __shared__ float Wl[NROW * KP];
    __shared__ float red[4 * Bc * 20];

    unsigned* flags0 = (unsigned*)wsf;            // [128] packed
    unsigned* flags1 = flags0 + 128;              // [128] packed
    float* h1b = wsf + H1_OFF;                    // [2][HBUF] transposed-chunked h[k/2][b][2]
    float* h2b = wsf + H2_OFF;

    const int wg  = blockIdx.x;
    const int tid = threadIdx.x;
    const bool isL1 = (wg >= NL0);
    const int j0 = (isL1 ? wg - NL0 : wg) * JPW;
    const int K  = isL1 ? 1024 : 768;
    const int KD = isL1 ? 512  : 256;

    // ---- one-time weight staging ----
    {
        const float* Wi = isL1 ? Wih1 : Wih0;
        const float* Wh = isL1 ? Whh1 : Whh0;
        for (int r = 0; r < NROW; ++r) {
            const int g = r >> 2, jj = r & 3;
            const int row = g * Hc + j0 + jj;
            for (int c = tid; c < K; c += NTHR)
                Wl[r * KP + c] = (c < KD) ? Wi[row * KD + c] : Wh[row * Hc + (c - KD)];
        }
    }
    __syncthreads();

    const int w     = tid >> 6;
    const int lane  = tid & 63;
    const int bgrp  = lane & 15;
    const int rbase = (lane >> 4) << 2;
    const int w8    = w * 8;
    const int NC    = K >> 6;    // chunks per wave: 12 / 16
    const int NCI   = KD >> 6;   // input-part chunks: 4 / 8

    const float* wr0 = &Wl[(rbase + 0) * KP];
    const float* wr1 = &Wl[(rbase + 1) * KP];
    const float* wr2 = &Wl[(rbase + 2) * KP];
    const float* wr3 = &Wl[(rbase + 3) * KP];

    // cell mapping: tid<256 -> (b = tid>>2, jj = tid&3)
    const int cb  = tid >> 2;
    const int cjj = tid & 3;
    const int hoff = ((j0 >> 1) + (cjj >> 1)) * 128 + cb * 2 + (cjj & 1);
    float cstate = 0.0f;
    float bias4[4];
    {
        const float* bi = isL1 ? bih1 : bih0;
        const float* bh = isL1 ? bhh1 : bhh0;
#pragma unroll
        for (int g = 0; g < 4; ++g)
            bias4[g] = bi[g * Hc + j0 + cjj] + bh[g * Hc + j0 + cjj];
    }

    unsigned* myflag = isL1 ? (flags1 + (wg - NL0)) : (flags0 + wg);

    for (int s = 0; s < Sc; ++s) {
        float acc[4][4];
#pragma unroll
        for (int i = 0; i < 4; ++i)
#pragma unroll
            for (int j = 0; j < 4; ++j) acc[i][j] = 0.0f;

        auto fma_block = [&](int kc, const float4* A, const float4* Bv) {
            const float4 wa0 = *(const float4*)(wr0 + kc), wb0 = *(const float4*)(wr0 + kc + 4);
            const float4 wa1 = *(const float4*)(wr1 + kc), wb1 = *(const float4*)(wr1 + kc + 4);
            const float4 wa2 = *(const float4*)(wr2 + kc), wb2 = *(const float4*)(wr2 + kc + 4);
            const float4 wa3 = *(const float4*)(wr3 + kc), wb3 = *(const float4*)(wr3 + kc + 4);
#pragma unroll
            for (int bb = 0; bb < 4; ++bb) {
                const float4 a = A[bb], b = Bv[bb];
                acc[bb][0] += wa0.x*a.x + wa0.y*a.y + wa0.z*a.z + wa0.w*a.w
                            + wb0.x*b.x + wb0.y*b.y + wb0.z*b.z + wb0.w*b.w;
                acc[bb][1] += wa1.x*a.x + wa1.y*a.y + wa1.z*a.z + wa1.w*a.w
                            + wb1.x*b.x + wb1.y*b.y + wb1.z*b.z + wb1.w*b.w;
                acc[bb][2] += wa2.x*a.x + wa2.y*a.y + wa2.z*a.z + wa2.w*a.w
                            + wb2.x*b.x + wb2.y*b.y + wb2.z*b.z + wb2.w*b.w;
                acc[bb][3] += wa3.x*a.x + wa3.y*a.y + wa3.z*a.z + wa3.w*a.w
                            + wb3.x*b.x + wb3.y*b.y + wb3.z*b.z + wb3.w*b.w;
            }
        };

        // h phase, quad-unrolled (all counts are multiples of 4): two pair-buffers
        // P,Q ping-pong with NO register copies; each pair's 32 sc1 loads are
        // issued 2 chunks (~700cy of compute) before first use.
        auto phase_h = [&](int cbeg, int cend, int sub, const float* hb_) {
            const float* hbb[4];
#pragma unroll
            for (int bb = 0; bb < 4; ++bb) hbb[bb] = hb_ + (bgrp + 16 * bb) * 2;
            auto ld = [&](int c, float4* A, float4* Bv) {
                const int c2 = (c * 64 + w8 - sub) >> 1;
#pragma unroll
                for (int bb = 0; bb < 4; ++bb) {
                    float2 p0 = cload2(hbb[bb] + (size_t)(c2 + 0) * 128);
                    float2 p1 = cload2(hbb[bb] + (size_t)(c2 + 1) * 128);
                    float2 p2 = cload2(hbb[bb] + (size_t)(c2 + 2) * 128);
                    float2 p3 = cload2(hbb[bb] + (size_t)(c2 + 3) * 128);
                    A[bb]  = make_float4(p0.x, p0.y, p1.x, p1.y);
                    Bv[bb] = make_float4(p2.x, p2.y, p3.x, p3.y);
                }
            };
            float4 Pa[4], Pb[4], Pc[4], Pd[4], Qa[4], Qb[4], Qc[4], Qd[4];
            ld(cbeg, Pa, Pb); ld(cbeg + 1, Pc, Pd);
            for (int c = cbeg; c < cend; c += 4) {
                ld(c + 2, Qa, Qb); ld(c + 3, Qc, Qd);
                fma_block(c * 64 + w8, Pa, Pb);
                fma_block((c + 1) * 64 + w8, Pc, Pd);
                if (c + 4 < cend) { ld(c + 4, Pa, Pb); ld(c + 5, Pc, Pd); }
                fma_block((c + 2) * 64 + w8, Qa, Qb);
                fma_block((c + 3) * 64 + w8, Qc, Qd);
            }
        };

        const float* h1rd = h1b + (size_t)((s + (isL1 ? 0 : 1)) & 1) * HBUF;

        if (!isL1) {
            // x-contribution: dependency-free, normal cached loads (L2-friendly)
            {
                const float* xb[4];
#pragma unroll
                for (int bb = 0; bb < 4; ++bb)
                    xb[bb] = x + (size_t)(bgrp + 16 * bb) * Sc * Dc + (size_t)s * Dc;
                auto ldx = [&](int c, float4* A, float4* Bv) {
                    const int kc = c * 64 + w8;
#pragma unroll
                    for (int bb = 0; bb < 4; ++bb) {
                        A[bb]  = *(const float4*)(xb[bb] + kc);
                        Bv[bb] = *(const float4*)(xb[bb] + kc + 4);
                    }
                };
                float4 Pa[4], Pb[4], Pc[4], Pd[4], Qa[4], Qb[4], Qc[4], Qd[4];
                ldx(0, Pa, Pb); ldx(1, Pc, Pd);
                ldx(2, Qa, Qb); ldx(3, Qc, Qd);
                fma_block(0 * 64 + w8, Pa, Pb);
                fma_block(1 * 64 + w8, Pc, Pd);
                fma_block(2 * 64 + w8, Qa, Qb);
                fma_block(3 * 64 + w8, Qc, Qd);
            }
            if (w == 0) {
                wait_layer(flags0, (unsigned)s, lane);                   // h1[s-1] ready
                wait_layer(flags1, (unsigned)(s > 0 ? s - 1 : 0), lane); // WAR vs L1
            }
            __syncthreads();
            phase_h(NCI, NC, KD, h1rd);
        } else {
            if (w == 0) wait_layer(flags1, (unsigned)s, lane);           // h2[s-1] ready (+WAR)
            __syncthreads();
            const float* h2rd = h2b + (size_t)((s + 1) & 1) * HBUF;
            phase_h(NCI, NC, KD, h2rd);      // own-layer recurrent half first
            if (w == 0) wait_layer(flags0, (unsigned)(s + 1), lane);     // h1[s] ready (tight edge)
            __syncthreads();
            phase_h(0, NCI, 0, h1rd);
        }

        // cross-wave K reduction
        if (w >= 4) {
#pragma unroll
            for (int bb = 0; bb < 4; ++bb) {
                const int b = bgrp + 16 * bb;
                *(float4*)&red[((w - 4) * Bc + b) * 20 + rbase] =
                    make_float4(acc[bb][0], acc[bb][1], acc[bb][2], acc[bb][3]);
            }
        }
        __syncthreads();
        if (w < 4) {
#pragma unroll
            for (int bb = 0; bb < 4; ++bb) {
                const int b = bgrp + 16 * bb;
                float4 p = *(float4*)&red[(w * Bc + b) * 20 + rbase];
                p.x += acc[bb][0]; p.y += acc[bb][1]; p.z += acc[bb][2]; p.w += acc[bb][3];
                *(float4*)&red[(w * Bc + b) * 20 + rbase] = p;
            }
        }
        __syncthreads();

        if (tid < 256) {
            float gv[4];
#pragma unroll
            for (int g = 0; g < 4; ++g) {
                const int r = g * 4 + cjj;
                gv[g] = red[(0 * Bc + cb) * 20 + r] + red[(1 * Bc + cb) * 20 + r]
                      + red[(2 * Bc + cb) * 20 + r] + red[(3 * Bc + cb) * 20 + r] + bias4[g];
            }
            const float ig = sigmoidf_fast(gv[0]);
            const float fg = sigmoidf_fast(gv[1]);
            const float gg = tanhf(gv[2]);
            const float og = sigmoidf_fast(gv[3]);
            cstate = fg * cstate + ig * gg;
            const float hv = og * tanhf(cstate);
            float* hb = (isL1 ? h2b : h1b) + (size_t)(s & 1) * HBUF;
            cstore1(hb + hoff, hv);
        }
        __syncthreads();   // drains h stores (vmcnt(0)) before publish
        if (tid == 0)
            __hip_atomic_store(myflag, (unsigned)(s + 1), __ATOMIC_RELAXED, __HIP_MEMORY_SCOPE_AGENT);
    }

    // ---- FC epilogue: WG b in [0,64) ----
    if (wg < Bc) {
        if (w == 0) wait_layer(flags1, (unsigned)Sc, lane);
        __syncthreads();
        const int b = wg;
        const float* h2 = h2b + (size_t)((Sc - 1) & 1) * HBUF;
        const int o = tid & 127, q = tid >> 7;
        const float* wrow = fcw + (size_t)o * Hc;
        float a = 0.0f;
        for (int k = q * 128; k < q * 128 + 128; k += 2) {
            const float2 hv = cload2(h2 + (size_t)(k >> 1) * 128 + b * 2);
            a += hv.x * wrow[k] + hv.y * wrow[k + 1];
        }
        __syncthreads();
        red[q * 128 + o] = a;
        __syncthreads();
        if (tid < OUTc)
            out[b * OUTc + tid] = red[tid] + red[128 + tid] + red[256 + tid] + red[384 + tid] + fcb[tid];
    }
}

extern "C" void kernel_launch(void* const* d_in, const int* in_sizes, int n_in,
                              void* d_out, int out_size, void* d_ws, size_t ws_size,
                              hipStream_t stream) {
    const float* x    = (const float*)d_in[0];
    const float* Wih0 = (const float*)d_in[1];
    const float* Whh0 = (const float*)d_in[2];
    const float* bih0 = (const float*)d_in[3];
    const float* bhh0 = (const float*)d_in[4];
    const float* Wih1 = (const float*)d_in[5];
    const float* Whh1 = (const float*)d_in[6];
    const float* bih1 = (const float*)d_in[7];
    const float* bhh1 = (const float*)d_in[8];
    const float* fcw  = (const float*)d_in[9];
    const float* fcb  = (const float*)d_in[10];
    float* out = (float*)d_out;
    float* wsf = (float*)d_ws;

    hipMemsetAsync(d_ws, 0, WS_BYTES, stream);

    lstm_persist<<<dim3(NWG), dim3(NTHR), 0, stream>>>(
        x, Wih0, Whh0, bih0, bhh0, Wih1, Whh1, bih1, bhh1, fcw, fcb, out, wsf);
}

// Round 7
// 31882.596 us; speedup vs baseline: 1.0003x; 1.0003x over previous
//
#include <hip/hip_runtime.h>
#include <cmath>

// Problem constants
#define Bc   64
#define Sc   512
#define Dc   256
#define Hc   512
#define OUTc 128

// Kernel config
#define NWG  256   // 128 layer0 + 128 layer1 workgroups, all resident (1/CU)
#define NTHR 512   // 8 waves, 2/SIMD
#define NL0  128
#define JPW  4
#define NROW 16
#define KP   1028  // padded LDS weight row stride

// h1 TRIPLE-buffered (decouples L0 from L1: WAR edge gets 2 steps of slack,
// so the two layer recurrences run concurrently instead of alternating).
// h2 double-buffered (only L1 reads it).
#define H1_OFF 1024                 // float offset (flags in bytes [0,1024))
#define HBUF (Bc * Hc)              // 32768 floats per h buffer
#define H2_OFF (H1_OFF + 3 * HBUF)
#define WS_BYTES ((H2_OFF + 2 * HBUF) * 4)   // ~644 KB

// ---- coherent accessors: relaxed agent-scope atomics (sc1), no cache flushes ----
__device__ __forceinline__ float2 cload2(const float* p) {
    unsigned long long u = __hip_atomic_load((const unsigned long long*)p,
                                             __ATOMIC_RELAXED, __HIP_MEMORY_SCOPE_AGENT);
    union { unsigned long long u; float2 f; } c; c.u = u; return c.f;
}
__device__ __forceinline__ void cstore1(float* p, float v) {
    union { float f; unsigned u; } c; c.f = v;
    __hip_atomic_store((unsigned*)p, c.u, __ATOMIC_RELAXED, __HIP_MEMORY_SCOPE_AGENT);
}

// per-WG monotonic step flags, packed (two coalesced 256B poll loads);
// ONLY wave 0 of a WG polls.
__device__ __forceinline__ void wait_layer(const unsigned* flags, unsigned target, int lane) {
    const unsigned* p0 = flags + lane;
    const unsigned* p1 = flags + lane + 64;
    for (;;) {
        unsigned f0 = __hip_atomic_load(p0, __ATOMIC_RELAXED, __HIP_MEMORY_SCOPE_AGENT);
        unsigned f1 = __hip_atomic_load(p1, __ATOMIC_RELAXED, __HIP_MEMORY_SCOPE_AGENT);
        if (__all((f0 >= target) && (f1 >= target))) return;
        __builtin_amdgcn_s_sleep(8);
    }
}

__device__ __forceinline__ float sigmoidf_fast(float v) {
    return 1.0f / (1.0f + __expf(-v));
}
__device__ __forceinline__ float tanhf_fast(float v) {
    // 2*sigmoid(2v)-1; __expf overflow at |v|>44 gives correct +/-1 limits
    return 2.0f / (1.0f + __expf(-2.0f * v)) - 1.0f;
}

extern "C" __global__ void __launch_bounds__(NTHR, 2)   // min 2 waves/EU -> VGPR cap 256 (r6 spilled at 128)
lstm_persist(const float* __restrict__ x,
             const float* __restrict__ Wih0, const float* __restrict__ Whh0,
             const float* __restrict__ bih0, const float* __restrict__ bhh0,
             const float* __restrict__ Wih1, const float* __restrict__ Whh1,
             const float* __restrict__ bih1, const float* __restrict__ bhh1,
             const float* __restrict__ fcw, const float* __restrict__ fcb,
             float* __restrict__ out, float* __restrict__ wsf)
{
    __shared__ float Wl[NROW * KP];
    __shared__ float red[4 * Bc * 20];

    unsigned* flags0 = (unsigned*)wsf;            // [128] packed
    unsigned* flags1 = flags0 + 128;              // [128] packed
    float* h1b = wsf + H1_OFF;                    // [3][HBUF] transposed-chunked h[k/2][b][2]
    float* h2b = wsf + H2_OFF;                    // [2][HBUF]

    const int wg  = blockIdx.x;
    const int tid = threadIdx.x;
    const bool isL1 = (wg >= NL0);
    const int j0 = (isL1 ? wg - NL0 : wg) * JPW;
    const int K  = isL1 ? 1024 : 768;
    const int KD = isL1 ? 512  : 256;

    // ---- one-time weight staging ----
    {
        const float* Wi = isL1 ? Wih1 : Wih0;
        const float* Wh = isL1 ? Whh1 : Whh0;
        for (int r = 0; r < NROW; ++r) {
            const int g = r >> 2, jj = r & 3;
            const int row = g * Hc + j0 + jj;
            for (int c = tid; c < K; c += NTHR)
                Wl[r * KP + c] = (c < KD) ? Wi[row * KD + c] : Wh[row * Hc + (c - KD)];
        }
    }
    __syncthreads();

    const int w     = tid >> 6;
    const int lane  = tid & 63;
    const int bgrp  = lane & 15;
    const int rbase = (lane >> 4) << 2;
    const int w8    = w * 8;
    const int NC    = K >> 6;    // chunks per wave: 12 / 16
    const int NCI   = KD >> 6;   // input-part chunks: 4 / 8

    const float* wr0 = &Wl[(rbase + 0) * KP];
    const float* wr1 = &Wl[(rbase + 1) * KP];
    const float* wr2 = &Wl[(rbase + 2) * KP];
    const float* wr3 = &Wl[(rbase + 3) * KP];

    // cell mapping: tid<256 -> (b = tid>>2, jj = tid&3)
    const int cb  = tid >> 2;
    const int cjj = tid & 3;
    const int hoff = ((j0 >> 1) + (cjj >> 1)) * 128 + cb * 2 + (cjj & 1);
    float cstate = 0.0f;
    float bias4[4];
    {
        const float* bi = isL1 ? bih1 : bih0;
        const float* bh = isL1 ? bhh1 : bhh0;
#pragma unroll
        for (int g = 0; g < 4; ++g)
            bias4[g] = bi[g * Hc + j0 + cjj] + bh[g * Hc + j0 + cjj];
    }

    unsigned* myflag = isL1 ? (flags1 + (wg - NL0)) : (flags0 + wg);

    for (int s = 0; s < Sc; ++s) {
        float acc[4][4];
#pragma unroll
        for (int i = 0; i < 4; ++i)
#pragma unroll
            for (int j = 0; j < 4; ++j) acc[i][j] = 0.0f;

        auto fma_block = [&](int kc, const float4* A, const float4* Bv) {
            const float4 wa0 = *(const float4*)(wr0 + kc), wb0 = *(const float4*)(wr0 + kc + 4);
            const float4 wa1 = *(const float4*)(wr1 + kc), wb1 = *(const float4*)(wr1 + kc + 4);
            const float4 wa2 = *(const float4*)(wr2 + kc), wb2 = *(const float4*)(wr2 + kc + 4);
            const float4 wa3 = *(const float4*)(wr3 + kc), wb3 = *(const float4*)(wr3 + kc + 4);
#pragma unroll
            for (int bb = 0; bb < 4; ++bb) {
                const float4 a = A[bb], b = Bv[bb];
                acc[bb][0] += wa0.x*a.x + wa0.y*a.y + wa0.z*a.z + wa0.w*a.w
                            + wb0.x*b.x + wb0.y*b.y + wb0.z*b.z + wb0.w*b.w;
                acc[bb][1] += wa1.x*a.x + wa1.y*a.y + wa1.z*a.z + wa1.w*a.w
                            + wb1.x*b.x + wb1.y*b.y + wb1.z*b.z + wb1.w*b.w;
                acc[bb][2] += wa2.x*a.x + wa2.y*a.y + wa2.z*a.z + wa2.w*a.w
                            + wb2.x*b.x + wb2.y*b.y + wb2.z*b.z + wb2.w*b.w;
                acc[bb][3] += wa3.x*a.x + wa3.y*a.y + wa3.z*a.z + wa3.w*a.w
                            + wb3.x*b.x + wb3.y*b.y + wb3.z*b.z + wb3.w*b.w;
            }
        };

        // h phase, quad-unrolled distance-2 prefetch (P/Q pair buffers, no reg
        // copies). ~210 VGPR demand — fits the 256 cap from launch_bounds(,2).
        auto phase_h = [&](int cbeg, int cend, int sub, const float* hb_) {
            const float* hbb[4];
#pragma unroll
            for (int bb = 0; bb < 4; ++bb) hbb[bb] = hb_ + (bgrp + 16 * bb) * 2;
            auto ld = [&](int c, float4* A, float4* Bv) {
                const int c2 = (c * 64 + w8 - sub) >> 1;
#pragma unroll
                for (int bb = 0; bb < 4; ++bb) {
                    float2 p0 = cload2(hbb[bb] + (size_t)(c2 + 0) * 128);
                    float2 p1 = cload2(hbb[bb] + (size_t)(c2 + 1) * 128);
                    float2 p2 = cload2(hbb[bb] + (size_t)(c2 + 2) * 128);
                    float2 p3 = cload2(hbb[bb] + (size_t)(c2 + 3) * 128);
                    A[bb]  = make_float4(p0.x, p0.y, p1.x, p1.y);
                    Bv[bb] = make_float4(p2.x, p2.y, p3.x, p3.y);
                }
            };
            float4 Pa[4], Pb[4], Pc[4], Pd[4], Qa[4], Qb[4], Qc[4], Qd[4];
            ld(cbeg, Pa, Pb); ld(cbeg + 1, Pc, Pd);
            for (int c = cbeg; c < cend; c += 4) {
                ld(c + 2, Qa, Qb); ld(c + 3, Qc, Qd);
                fma_block(c * 64 + w8, Pa, Pb);
                fma_block((c + 1) * 64 + w8, Pc, Pd);
                if (c + 4 < cend) { ld(c + 4, Pa, Pb); ld(c + 5, Pc, Pd); }
                fma_block((c + 2) * 64 + w8, Qa, Qb);
                fma_block((c + 3) * 64 + w8, Qc, Qd);
            }
        };

        // h1 ring indices (mod 3)
        const int mW = s % 3;              // L0 writes h1[s] here; L1 reads h1[s] here
        const int mR = (s + 2) % 3;        // h1[s-1] (L0 recurrent read)

        if (!isL1) {
            // x-contribution: dependency-free, overlaps producer stragglers
            {
                const float* xb[4];
#pragma unroll
                for (int bb = 0; bb < 4; ++bb)
                    xb[bb] = x + (size_t)(bgrp + 16 * bb) * Sc * Dc + (size_t)s * Dc;
                auto ldx = [&](int c, float4* A, float4* Bv) {
                    const int kc = c * 64 + w8;
#pragma unroll
                    for (int bb = 0; bb < 4; ++bb) {
                        A[bb]  = *(const float4*)(xb[bb] + kc);
                        Bv[bb] = *(const float4*)(xb[bb] + kc + 4);
                    }
                };
                float4 Pa[4], Pb[4], Pc[4], Pd[4], Qa[4], Qb[4], Qc[4], Qd[4];
                ldx(0, Pa, Pb); ldx(1, Pc, Pd);
                ldx(2, Qa, Qb); ldx(3, Qc, Qd);
                fma_block(0 * 64 + w8, Pa, Pb);
                fma_block(1 * 64 + w8, Pc, Pd);
                fma_block(2 * 64 + w8, Qa, Qb);
                fma_block(3 * 64 + w8, Qc, Qd);
            }
            if (w == 0) {
                wait_layer(flags0, (unsigned)s, lane);                    // h1[s-1] ready (intra-layer)
                wait_layer(flags1, (unsigned)(s >= 3 ? s - 2 : 0), lane); // WAR: L1 done reading h1[s-3]
            }
            __syncthreads();
            phase_h(NCI, NC, KD, h1b + (size_t)mR * HBUF);
        } else {
            if (w == 0) wait_layer(flags1, (unsigned)s, lane);            // h2[s-1] ready (+h2 WAR)
            __syncthreads();
            phase_h(NCI, NC, KD, h2b + (size_t)((s + 1) & 1) * HBUF);     // own recurrent half first
            if (w == 0) wait_layer(flags0, (unsigned)(s + 1), lane);      // h1[s] ready (usually already)
            __syncthreads();
            phase_h(0, NCI, 0, h1b + (size_t)mW * HBUF);
        }

        // cross-wave K reduction
        if (w >= 4) {
#pragma unroll
            for (int bb = 0; bb < 4; ++bb) {
                const int b = bgrp + 16 * bb;
                *(float4*)&red[((w - 4) * Bc + b) * 20 + rbase] =
                    make_float4(acc[bb][0], acc[bb][1], acc[bb][2], acc[bb][3]);
            }
        }
        __syncthreads();
        if (w < 4) {
#pragma unroll
            for (int bb = 0; bb < 4; ++bb) {
                const int b = bgrp + 16 * bb;
                float4 p = *(float4*)&red[(w * Bc + b) * 20 + rbase];
                p.x += acc[bb][0]; p.y += acc[bb][1]; p.z += acc[bb][2]; p.w += acc[bb][3];
                *(float4*)&red[(w * Bc + b) * 20 + rbase] = p;
            }
        }
        __syncthreads();

        if (tid < 256) {
            float gv[4];
#pragma unroll
            for (int g = 0; g < 4; ++g) {
                const int r = g * 4 + cjj;
                gv[g] = red[(0 * Bc + cb) * 20 + r] + red[(1 * Bc + cb) * 20 + r]
                      + red[(2 * Bc + cb) * 20 + r] + red[(3 * Bc + cb) * 20 + r] + bias4[g];
            }
            const float ig = sigmoidf_fast(gv[0]);
            const float fg = sigmoidf_fast(gv[1]);
            const float gg = tanhf_fast(gv[2]);
            const float og = sigmoidf_fast(gv[3]);
            cstate = fg * cstate + ig * gg;
            const float hv = og * tanhf_fast(cstate);
            float* hb = isL1 ? (h2b + (size_t)(s & 1) * HBUF)
                             : (h1b + (size_t)mW * HBUF);
            cstore1(hb + hoff, hv);
        }
        __syncthreads();   // drains h stores (vmcnt(0)) before publish
        if (tid == 0)
            __hip_atomic_store(myflag, (unsigned)(s + 1), __ATOMIC_RELAXED, __HIP_MEMORY_SCOPE_AGENT);
    }

    // ---- FC epilogue: WG b in [0,64) ----
    if (wg < Bc) {
        if (w == 0) wait_layer(flags1, (unsigned)Sc, lane);
        __syncthreads();
        const int b = wg;
        const float* h2 = h2b + (size_t)((Sc - 1) & 1) * HBUF;
        const int o = tid & 127, q = tid >> 7;
        const float* wrow = fcw + (size_t)o * Hc;
        float a = 0.0f;
        for (int k = q * 128; k < q * 128 + 128; k += 2) {
            const float2 hv = cload2(h2 + (size_t)(k >> 1) * 128 + b * 2);
            a += hv.x * wrow[k] + hv.y * wrow[k + 1];
        }
        __syncthreads();
        red[q * 128 + o] = a;
        __syncthreads();
        if (tid < OUTc)
            out[b * OUTc + tid] = red[tid] + red[128 + tid] + red[256 + tid] + red[384 + tid] + fcb[tid];
    }
}

extern "C" void kernel_launch(void* const* d_in, const int* in_sizes, int n_in,
                              void* d_out, int out_size, void* d_ws, size_t ws_size,
                              hipStream_t stream) {
    const float* x    = (const float*)d_in[0];
    const float* Wih0 = (const float*)d_in[1];
    const float* Whh0 = (const float*)d_in[2];
    const float* bih0 = (const float*)d_in[3];
    const float* bhh0 = (const float*)d_in[4];
    const float* Wih1 = (const float*)d_in[5];
    const float* Whh1 = (const float*)d_in[6];
    const float* bih1 = (const float*)d_in[7];
    const float* bhh1 = (const float*)d_in[8];
    const float* fcw  = (const float*)d_in[9];
    const float* fcb  = (const float*)d_in[10];
    float* out = (float*)d_out;
    float* wsf = (float*)d_ws;

    hipMemsetAsync(d_ws, 0, WS_BYTES, stream);

    lstm_persist<<<dim3(NWG), dim3(NTHR), 0, stream>>>(
        x, Wih0, Whh0, bih0, bhh0, Wih1, Whh1, bih1, bhh1, fcw, fcb, out, wsf);
}

// Round 8
// 9917.156 us; speedup vs baseline: 3.2158x; 3.2149x over previous
//
#include <hip/hip_runtime.h>
#include <cmath>

typedef unsigned long long u64;
typedef unsigned int u32;

// Problem constants
#define Bc   64
#define Sc   512
#define Dc   256
#define Hc   512
#define OUTc 128

// Kernel config
#define NWG  256   // 128 layer0 + 128 layer1 workgroups, all resident (1/CU)
#define NTHR 512   // 8 waves, 2/SIMD (1 WG/CU: LDS 86.5 KB)
#define NL0  128
#define JPW  4
#define NROW 16
#define KP   1028  // padded LDS weight row stride

// h exchanged as PACKED BF16: u64 = 4 values along k for one batch.
// Layout: hu64[q][b], q = k/4 (0..127), b = 0..63  -> 64 KB per buffer.
// h1 triple-buffered (L0/L1 decoupling), h2 double-buffered.
#define HQ   8192                   // u64s per h buffer (64*512/4)
#define WS_BYTES (4096 + 5 * HQ * 8)   // flags 1KB @0, h bufs @4096: 331776 B

// ---- coherent accessors: relaxed agent-scope atomics (sc1), no cache flushes ----
__device__ __forceinline__ u64 cload8(const u64* p) {
    return __hip_atomic_load(p, __ATOMIC_RELAXED, __HIP_MEMORY_SCOPE_AGENT);
}
__device__ __forceinline__ void cstore4(u32* p, u32 v) {
    __hip_atomic_store(p, v, __ATOMIC_RELAXED, __HIP_MEMORY_SCOPE_AGENT);
}

// bf16x4 -> float4 (lo16 of each u32 is the even-k value)
__device__ __forceinline__ float4 unpack4(u64 v) {
    u32 lo = (u32)v, hi = (u32)(v >> 32);
    float4 f;
    f.x = __uint_as_float(lo << 16);
    f.y = __uint_as_float(lo & 0xffff0000u);
    f.z = __uint_as_float(hi << 16);
    f.w = __uint_as_float(hi & 0xffff0000u);
    return f;
}
// two floats -> packed bf16x2 (RNE)
__device__ __forceinline__ u32 pack2_rne(float a, float b) {
    u32 ua = __float_as_uint(a), ub = __float_as_uint(b);
    ua += 0x7fffu + ((ua >> 16) & 1u);
    ub += 0x7fffu + ((ub >> 16) & 1u);
    return (ua >> 16) | (ub & 0xffff0000u);
}

// per-WG monotonic step flags, packed; ONLY wave 0 of a WG polls.
__device__ __forceinline__ void wait_layer(const u32* flags, u32 target, int lane) {
    const u32* p0 = flags + lane;
    const u32* p1 = flags + lane + 64;
    for (;;) {
        u32 f0 = __hip_atomic_load(p0, __ATOMIC_RELAXED, __HIP_MEMORY_SCOPE_AGENT);
        u32 f1 = __hip_atomic_load(p1, __ATOMIC_RELAXED, __HIP_MEMORY_SCOPE_AGENT);
        if (__all((f0 >= target) && (f1 >= target))) return;
        __builtin_amdgcn_s_sleep(8);
    }
}

__device__ __forceinline__ float sigmoidf_fast(float v) {
    return 1.0f / (1.0f + __expf(-v));
}
__device__ __forceinline__ float tanhf_fast(float v) {
    return 2.0f / (1.0f + __expf(-2.0f * v)) - 1.0f;
}

extern "C" __global__ void __launch_bounds__(NTHR)
__attribute__((amdgpu_waves_per_eu(2, 2)))   // pin occupancy target: VGPR budget 256 (r6/r7 spilled at the default 128 cap)
lstm_persist(const float* __restrict__ x,
             const float* __restrict__ Wih0, const float* __restrict__ Whh0,
             const float* __restrict__ bih0, const float* __restrict__ bhh0,
             const float* __restrict__ Wih1, const float* __restrict__ Whh1,
             const float* __restrict__ bih1, const float* __restrict__ bhh1,
             const float* __restrict__ fcw, const float* __restrict__ fcb,
             float* __restrict__ out, float* __restrict__ wsf)
{
    __shared__ float Wl[NROW * KP];
    __shared__ float red[4 * Bc * 20];

    u32* flags0 = (u32*)wsf;                       // [128] packed
    u32* flags1 = flags0 + 128;                    // [128] packed
    u64* h1b = (u64*)((char*)wsf + 4096);          // [3][HQ]
    u64* h2b = h1b + 3 * HQ;                       // [2][HQ]

    const int wg  = blockIdx.x;
    const int tid = threadIdx.x;
    const bool isL1 = (wg >= NL0);
    const int j0 = (isL1 ? wg - NL0 : wg) * JPW;
    const int K  = isL1 ? 1024 : 768;
    const int KD = isL1 ? 512  : 256;

    // ---- one-time weight staging (fp32) ----
    {
        const float* Wi = isL1 ? Wih1 : Wih0;
        const float* Wh = isL1 ? Whh1 : Whh0;
        for (int r = 0; r < NROW; ++r) {
            const int g = r >> 2, jj = r & 3;
            const int row = g * Hc + j0 + jj;
            for (int c = tid; c < K; c += NTHR)
                Wl[r * KP + c] = (c < KD) ? Wi[row * KD + c] : Wh[row * Hc + (c - KD)];
        }
    }
    __syncthreads();

    const int w     = tid >> 6;
    const int lane  = tid & 63;
    const int bgrp  = lane & 15;
    const int rbase = (lane >> 4) << 2;
    const int w8    = w * 8;
    const int NC    = K >> 6;    // chunks per wave: 12 / 16
    const int NCI   = KD >> 6;   // input-part chunks: 4 / 8

    const float* wr0 = &Wl[(rbase + 0) * KP];
    const float* wr1 = &Wl[(rbase + 1) * KP];
    const float* wr2 = &Wl[(rbase + 2) * KP];
    const float* wr3 = &Wl[(rbase + 3) * KP];

    // ---- cell mapping: tid<128 -> (b = tid>>1, jpair = tid&1), 2 cells each ----
    const int cb    = tid >> 1;
    const int jpair = tid & 1;
    float cst[2] = {0.0f, 0.0f};
    float bias2[2][4];
    {
        const float* bi = isL1 ? bih1 : bih0;
        const float* bh = isL1 ? bhh1 : bhh0;
#pragma unroll
        for (int jj2 = 0; jj2 < 2; ++jj2) {
            const int j = j0 + 2 * jpair + jj2;
#pragma unroll
            for (int g = 0; g < 4; ++g)
                bias2[jj2][g] = bi[g * Hc + j] + bh[g * Hc + j];
        }
    }
    // h store slot: u32 index = (j0>>2)*128 + tid  (512B contiguous per WG)
    const int hsoff = (j0 >> 2) * 128 + tid;

    u32* myflag = isL1 ? (flags1 + (wg - NL0)) : (flags0 + wg);

    for (int s = 0; s < Sc; ++s) {
        float acc[4][4];
#pragma unroll
        for (int i = 0; i < 4; ++i)
#pragma unroll
            for (int j = 0; j < 4; ++j) acc[i][j] = 0.0f;

        // FMA of one 8-k chunk from packed bf16 (D[8]: [bb]{lo,hi} u64s)
        auto fma_chunkp = [&](int kc, const u64* D) {
            const float4 wa0 = *(const float4*)(wr0 + kc), wb0 = *(const float4*)(wr0 + kc + 4);
            const float4 wa1 = *(const float4*)(wr1 + kc), wb1 = *(const float4*)(wr1 + kc + 4);
            const float4 wa2 = *(const float4*)(wr2 + kc), wb2 = *(const float4*)(wr2 + kc + 4);
            const float4 wa3 = *(const float4*)(wr3 + kc), wb3 = *(const float4*)(wr3 + kc + 4);
#pragma unroll
            for (int bb = 0; bb < 4; ++bb) {
                const float4 a = unpack4(D[bb * 2 + 0]);
                const float4 b = unpack4(D[bb * 2 + 1]);
                acc[bb][0] += wa0.x*a.x + wa0.y*a.y + wa0.z*a.z + wa0.w*a.w
                            + wb0.x*b.x + wb0.y*b.y + wb0.z*b.z + wb0.w*b.w;
                acc[bb][1] += wa1.x*a.x + wa1.y*a.y + wa1.z*a.z + wa1.w*a.w
                            + wb1.x*b.x + wb1.y*b.y + wb1.z*b.z + wb1.w*b.w;
                acc[bb][2] += wa2.x*a.x + wa2.y*a.y + wa2.z*a.z + wa2.w*a.w
                            + wb2.x*b.x + wb2.y*b.y + wb2.z*b.z + wb2.w*b.w;
                acc[bb][3] += wa3.x*a.x + wa3.y*a.y + wa3.z*a.z + wa3.w*a.w
                            + wb3.x*b.x + wb3.y*b.y + wb3.z*b.z + wb3.w*b.w;
            }
        };

        // h phase: quad-unrolled, distance-2-chunk prefetch, 8 u64 sc1 loads/chunk
        auto phase_h = [&](int cbeg, int cend, int sub, const u64* hb_) {
            auto ld = [&](int c, u64* D) {
                const int q = (c * 64 + w8 - sub) >> 2;
                const u64* base = hb_ + (size_t)q * 64;
#pragma unroll
                for (int bb = 0; bb < 4; ++bb) {
                    const int b = bgrp + 16 * bb;
                    D[bb * 2 + 0] = cload8(base + b);
                    D[bb * 2 + 1] = cload8(base + 64 + b);
                }
            };
            u64 P[16], Q[16];
            ld(cbeg, P); ld(cbeg + 1, P + 8);
            for (int c = cbeg; c < cend; c += 4) {
                ld(c + 2, Q); ld(c + 3, Q + 8);
                fma_chunkp(c * 64 + w8, P);
                fma_chunkp((c + 1) * 64 + w8, P + 8);
                if (c + 4 < cend) { ld(c + 4, P); ld(c + 5, P + 8); }
                fma_chunkp((c + 2) * 64 + w8, Q);
                fma_chunkp((c + 3) * 64 + w8, Q + 8);
            }
        };

        // h1 ring indices (mod 3)
        const int mW = s % 3;              // L0 writes h1[s]; L1 reads h1[s]
        const int mR = (s + 2) % 3;        // h1[s-1] (L0 recurrent read)

        if (!isL1) {
            // x-contribution: dependency-free fp32 (L2-cached), 4 chunks
            {
                const float* xb[4];
#pragma unroll
                for (int bb = 0; bb < 4; ++bb)
                    xb[bb] = x + (size_t)(bgrp + 16 * bb) * Sc * Dc + (size_t)s * Dc;
                auto fma_f32 = [&](int kc, const float4* A, const float4* Bv) {
                    const float4 wa0 = *(const float4*)(wr0 + kc), wb0 = *(const float4*)(wr0 + kc + 4);
                    const float4 wa1 = *(const float4*)(wr1 + kc), wb1 = *(const float4*)(wr1 + kc + 4);
                    const float4 wa2 = *(const float4*)(wr2 + kc), wb2 = *(const float4*)(wr2 + kc + 4);
                    const float4 wa3 = *(const float4*)(wr3 + kc), wb3 = *(const float4*)(wr3 + kc + 4);
#pragma unroll
                    for (int bb = 0; bb < 4; ++bb) {
                        const float4 a = A[bb], b = Bv[bb];
                        acc[bb][0] += wa0.x*a.x + wa0.y*a.y + wa0.z*a.z + wa0.w*a.w
                                    + wb0.x*b.x + wb0.y*b.y + wb0.z*b.z + wb0.w*b.w;
                        acc[bb][1] += wa1.x*a.x + wa1.y*a.y + wa1.z*a.z + wa1.w*a.w
                                    + wb1.x*b.x + wb1.y*b.y + wb1.z*b.z + wb1.w*b.w;
                        acc[bb][2] += wa2.x*a.x + wa2.y*a.y + wa2.z*a.z + wa2.w*a.w
                                    + wb2.x*b.x + wb2.y*b.y + wb2.z*b.z + wb2.w*b.w;
                        acc[bb][3] += wa3.x*a.x + wa3.y*a.y + wa3.z*a.z + wa3.w*a.w
                                    + wb3.x*b.x + wb3.y*b.y + wb3.z*b.z + wb3.w*b.w;
                    }
                };
                auto ldx = [&](int c, float4* A, float4* Bv) {
                    const int kc = c * 64 + w8;
#pragma unroll
                    for (int bb = 0; bb < 4; ++bb) {
                        A[bb]  = *(const float4*)(xb[bb] + kc);
                        Bv[bb] = *(const float4*)(xb[bb] + kc + 4);
                    }
                };
                float4 Pa[4], Pb[4], Pc[4], Pd[4], Qa[4], Qb[4], Qc[4], Qd[4];
                ldx(0, Pa, Pb); ldx(1, Pc, Pd);
                ldx(2, Qa, Qb); ldx(3, Qc, Qd);
                fma_f32(0 * 64 + w8, Pa, Pb);
                fma_f32(1 * 64 + w8, Pc, Pd);
                fma_f32(2 * 64 + w8, Qa, Qb);
                fma_f32(3 * 64 + w8, Qc, Qd);
            }
            if (w == 0) {
                wait_layer(flags0, (u32)s, lane);                    // h1[s-1] ready
                wait_layer(flags1, (u32)(s >= 3 ? s - 2 : 0), lane); // WAR: L1 done with h1[s-3]
            }
            __syncthreads();
            phase_h(NCI, NC, KD, h1b + (size_t)mR * HQ);
        } else {
            if (w == 0) wait_layer(flags1, (u32)s, lane);            // h2[s-1] ready (+h2 WAR)
            __syncthreads();
            phase_h(NCI, NC, KD, h2b + (size_t)((s + 1) & 1) * HQ);  // own recurrent half first
            if (w == 0) wait_layer(flags0, (u32)(s + 1), lane);      // h1[s] ready (L0 runs ahead)
            __syncthreads();
            phase_h(0, NCI, 0, h1b + (size_t)mW * HQ);
        }

        // cross-wave K reduction
        if (w >= 4) {
#pragma unroll
            for (int bb = 0; bb < 4; ++bb) {
                const int b = bgrp + 16 * bb;
                *(float4*)&red[((w - 4) * Bc + b) * 20 + rbase] =
                    make_float4(acc[bb][0], acc[bb][1], acc[bb][2], acc[bb][3]);
            }
        }
        __syncthreads();
        if (w < 4) {
#pragma unroll
            for (int bb = 0; bb < 4; ++bb) {
                const int b = bgrp + 16 * bb;
                float4 p = *(float4*)&red[(w * Bc + b) * 20 + rbase];
                p.x += acc[bb][0]; p.y += acc[bb][1]; p.z += acc[bb][2]; p.w += acc[bb][3];
                *(float4*)&red[(w * Bc + b) * 20 + rbase] = p;
            }
        }
        __syncthreads();

        if (tid < 128) {
            float hv[2];
#pragma unroll
            for (int jj2 = 0; jj2 < 2; ++jj2) {
                const int jj = 2 * jpair + jj2;
                float gv[4];
#pragma unroll
                for (int g = 0; g < 4; ++g) {
                    const int r = g * 4 + jj;
                    gv[g] = red[(0 * Bc + cb) * 20 + r] + red[(1 * Bc + cb) * 20 + r]
                          + red[(2 * Bc + cb) * 20 + r] + red[(3 * Bc + cb) * 20 + r]
                          + bias2[jj2][g];
                }
                const float ig = sigmoidf_fast(gv[0]);
                const float fg = sigmoidf_fast(gv[1]);
                const float gg = tanhf_fast(gv[2]);
                const float og = sigmoidf_fast(gv[3]);
                cst[jj2] = fg * cst[jj2] + ig * gg;
                hv[jj2] = og * tanhf_fast(cst[jj2]);
            }
            u64* hb = isL1 ? (h2b + (size_t)(s & 1) * HQ)
                           : (h1b + (size_t)mW * HQ);
            cstore4((u32*)hb + hsoff, pack2_rne(hv[0], hv[1]));
        }
        __syncthreads();   // drains h stores (vmcnt(0)) before publish
        if (tid == 0)
            __hip_atomic_store(myflag, (u32)(s + 1), __ATOMIC_RELAXED, __HIP_MEMORY_SCOPE_AGENT);
    }

    // ---- FC epilogue: WG b in [0,64) ----
    if (wg < Bc) {
        if (w == 0) wait_layer(flags1, (u32)Sc, lane);
        __syncthreads();
        const int b = wg;
        const u64* h2 = h2b + (size_t)((Sc - 1) & 1) * HQ;
        const int o = tid & 127, q = tid >> 7;
        const float* wrow = fcw + (size_t)o * Hc;
        float a = 0.0f;
        for (int k4 = q * 32; k4 < q * 32 + 32; ++k4) {
            const float4 f = unpack4(cload8(h2 + (size_t)k4 * 64 + b));
            const float* wr = wrow + 4 * k4;
            a += f.x * wr[0] + f.y * wr[1] + f.z * wr[2] + f.w * wr[3];
        }
        __syncthreads();
        red[q * 128 + o] = a;
        __syncthreads();
        if (tid < OUTc)
            out[b * OUTc + tid] = red[tid] + red[128 + tid] + red[256 + tid] + red[384 + tid] + fcb[tid];
    }
}

extern "C" void kernel_launch(void* const* d_in, const int* in_sizes, int n_in,
                              void* d_out, int out_size, void* d_ws, size_t ws_size,
                              hipStream_t stream) {
    const float* x    = (const float*)d_in[0];
    const float* Wih0 = (const float*)d_in[1];
    const float* Whh0 = (const float*)d_in[2];
    const float* bih0 = (const float*)d_in[3];
    const float* bhh0 = (const float*)d_in[4];
    const float* Wih1 = (const float*)d_in[5];
    const float* Whh1 = (const float*)d_in[6];
    const float* bih1 = (const float*)d_in[7];
    const float* bhh1 = (const float*)d_in[8];
    const float* fcw  = (const float*)d_in[9];
    const float* fcb  = (const float*)d_in[10];
    float* out = (float*)d_out;
    float* wsf = (float*)d_ws;

    hipMemsetAsync(d_ws, 0, WS_BYTES, stream);   // zero flags + h (h[-1]=0; bf16 zero = 0 bits)

    lstm_persist<<<dim3(NWG), dim3(NTHR), 0, stream>>>(
        x, Wih0, Whh0, bih0, bhh0, Wih1, Whh1, bih1, bhh1, fcw, fcb, out, wsf);
}

// Round 9
// 2163.325 us; speedup vs baseline: 14.7420x; 4.5842x over previous
//
#include <hip/hip_runtime.h>

typedef unsigned long long u64;
typedef unsigned int u32;
typedef __attribute__((ext_vector_type(8))) short short8;   // bf16x8 MFMA frag
typedef __attribute__((ext_vector_type(4))) float floatx4;  // f32x4 MFMA acc

// Problem constants
#define Bc   64
#define Sc   512
#define Dc   256
#define Hc   512
#define OUTc 128

// Kernel config: WG = (row-group rg 0..31, batch-group bg 0..3) per layer.
// WG owns 64 weight rows (4 gates x 16 j) x 16 batches. 8 waves = (gate g, K-half).
#define NWG  256
#define NTHR 512
#define NL0  128
#define JPW  16     // j indices per WG
#define NRW  64     // weight rows per WG
#define KPB  1032   // bf16 LDS row stride (max K 1024 + 8 pad)

#define HQ   8192   // u64s per h buffer: hu64[k/4][b]
#define WS_BYTES (4096 + 5 * HQ * 8)

// ---- coherent accessors: relaxed agent-scope atomics (sc1) ----
__device__ __forceinline__ u64 cload8(const u64* p) {
    return __hip_atomic_load(p, __ATOMIC_RELAXED, __HIP_MEMORY_SCOPE_AGENT);
}
__device__ __forceinline__ void cstore4(u32* p, u32 v) {
    __hip_atomic_store(p, v, __ATOMIC_RELAXED, __HIP_MEMORY_SCOPE_AGENT);
}

__device__ __forceinline__ short bf16_rne(float f) {
    u32 u = __float_as_uint(f);
    u += 0x7fffu + ((u >> 16) & 1u);
    return (short)(u >> 16);
}
__device__ __forceinline__ float4 unpack4(u64 v) {   // FC epilogue only
    u32 lo = (u32)v, hi = (u32)(v >> 32);
    float4 f;
    f.x = __uint_as_float(lo << 16);
    f.y = __uint_as_float(lo & 0xffff0000u);
    f.z = __uint_as_float(hi << 16);
    f.w = __uint_as_float(hi & 0xffff0000u);
    return f;
}
__device__ __forceinline__ u32 pack2_rne(float a, float b) {
    u32 ua = __float_as_uint(a), ub = __float_as_uint(b);
    ua += 0x7fffu + ((ua >> 16) & 1u);
    ub += 0x7fffu + ((ub >> 16) & 1u);
    return (ua >> 16) | (ub & 0xffff0000u);
}
__device__ __forceinline__ short8 frag2(u64 a, u64 b) {
    union { u64 u[2]; short8 s; } c; c.u[0] = a; c.u[1] = b; return c.s;
}

// poll 32 same-bg producer flags: one 128B MALL line per iteration. wave0 only.
__device__ __forceinline__ void wait32(const u32* fbase, u32 target, int lane) {
    const u32* p = fbase + (lane & 31);
    for (;;) {
        u32 f = __hip_atomic_load(p, __ATOMIC_RELAXED, __HIP_MEMORY_SCOPE_AGENT);
        if (__all(f >= target)) return;
        __builtin_amdgcn_s_sleep(8);
    }
}
__device__ __forceinline__ void wait128(const u32* flags, u32 target, int lane) {
    const u32* p0 = flags + lane; const u32* p1 = flags + lane + 64;
    for (;;) {
        u32 f0 = __hip_atomic_load(p0, __ATOMIC_RELAXED, __HIP_MEMORY_SCOPE_AGENT);
        u32 f1 = __hip_atomic_load(p1, __ATOMIC_RELAXED, __HIP_MEMORY_SCOPE_AGENT);
        if (__all((f0 >= target) && (f1 >= target))) return;
        __builtin_amdgcn_s_sleep(8);
    }
}

__device__ __forceinline__ float sigmoidf_fast(float v) {
    return 1.0f / (1.0f + __expf(-v));
}
__device__ __forceinline__ float tanhf_fast(float v) {
    return 2.0f / (1.0f + __expf(-2.0f * v)) - 1.0f;
}

extern "C" __global__ void __launch_bounds__(NTHR)
lstm_persist(const float* __restrict__ x,
             const float* __restrict__ Wih0, const float* __restrict__ Whh0,
             const float* __restrict__ bih0, const float* __restrict__ bhh0,
             const float* __restrict__ Wih1, const float* __restrict__ Whh1,
             const float* __restrict__ bih1, const float* __restrict__ bhh1,
             const float* __restrict__ fcw, const float* __restrict__ fcb,
             float* __restrict__ out, float* __restrict__ wsf)
{
    __shared__ short Wl[NRW * KPB];          // 132 KB bf16 weights, resident
    __shared__ float red[2 * 4 * 16 * 20];   // 10.2 KB: [half][gate][b16][jl pad20]

    u32* flags0 = (u32*)wsf;                 // [4 bg][32 rg]
    u32* flags1 = flags0 + 128;
    u64* h1b = (u64*)((char*)wsf + 4096);    // [3][HQ]
    u64* h2b = h1b + 3 * HQ;                 // [2][HQ]

    const int wg  = blockIdx.x;
    const int tid = threadIdx.x;
    const bool isL1 = (wg >= NL0);
    const int wgl = isL1 ? wg - NL0 : wg;
    const int rg = wgl >> 2, bg = wgl & 3;
    const int j0 = rg * JPW;
    const int K  = isL1 ? 1024 : 768;
    const int KD = isL1 ? 512  : 256;

    // ---- one-time weight staging: 64 rows (g*16+jl) x K, fp32 -> bf16 ----
    {
        const float* Wi = isL1 ? Wih1 : Wih0;
        const float* Wh = isL1 ? Whh1 : Whh0;
        for (int r = 0; r < NRW; ++r) {
            const int row = (r >> 4) * Hc + j0 + (r & 15);
            for (int c = tid; c < K; c += NTHR) {
                float v = (c < KD) ? Wi[(size_t)row * KD + c] : Wh[(size_t)row * Hc + (c - KD)];
                Wl[r * KPB + c] = bf16_rne(v);
            }
        }
    }
    __syncthreads();

    // ---- wave mapping: w = (gate g)*2 + K-half ----
    const int w    = tid >> 6;
    const int lane = tid & 63;
    const int g    = w >> 1;
    const int half = w & 1;
    const int quad = lane >> 4;
    const int c16  = lane & 15;
    const int bglob = bg * 16 + c16;                    // B-frag batch (n = lane&15)
    const int wrowb = (g * 16 + c16) * KPB;             // A-frag row (m = lane&15)

    // ---- cell mapping: tid<128 -> (bl = tid&15, jp = tid>>4), 2 cells (j pair) ----
    const int bl = tid & 15, jp = tid >> 4;
    float cst[2] = {0.0f, 0.0f};
    float bias2[2][4];
    {
        const float* bi = isL1 ? bih1 : bih0;
        const float* bh = isL1 ? bhh1 : bhh0;
#pragma unroll
        for (int jj2 = 0; jj2 < 2; ++jj2) {
            const int j = j0 + 2 * jp + jj2;
#pragma unroll
            for (int gg = 0; gg < 4; ++gg)
                bias2[jj2][gg] = bi[gg * Hc + j] + bh[gg * Hc + j];
        }
    }
    const int hsoff = ((j0 + 2 * jp) >> 2) * 128 + 2 * (bg * 16 + bl) + (jp & 1);

    u32* myflag = (isL1 ? flags1 : flags0) + bg * 32 + rg;
    const u32* f0b = flags0 + bg * 32;
    const u32* f1b = flags1 + bg * 32;

    for (int s = 0; s < Sc; ++s) {
        floatx4 acc = {0.0f, 0.0f, 0.0f, 0.0f};

        // MFMA phase over nblk K-blocks: issue ALL sc1 B-loads up front, then
        // ds_read A + mfma. wk0 = weight col start; hk0 = col start in h buffer.
        auto mfma_h = [&](int wk0, int hk0, int nblk, const u64* hb_) {
            u64 F[16];
#pragma unroll
            for (int i = 0; i < 8; ++i) {
                if (i >= nblk) break;
                const int q8 = (hk0 >> 2) + i * 8 + quad * 2;
                F[2 * i]     = cload8(hb_ + (size_t)q8 * 64 + bglob);
                F[2 * i + 1] = cload8(hb_ + (size_t)(q8 + 1) * 64 + bglob);
            }
#pragma unroll
            for (int i = 0; i < 8; ++i) {
                if (i >= nblk) break;
                short8 A = *(const short8*)&Wl[wrowb + wk0 + i * 32 + quad * 8];
                short8 Bv = frag2(F[2 * i], F[2 * i + 1]);
                acc = __builtin_amdgcn_mfma_f32_16x16x32_bf16(A, Bv, acc, 0, 0, 0);
            }
        };

        const int mW = s % 3;            // h1[s] slot (L0 write, L1 read)
        const int mR = (s + 2) % 3;      // h1[s-1] slot (L0 recurrent read)

        if (!isL1) {
            // x-phase: dependency-free; fp32 x -> bf16 B-frag on the fly
            {
                const float* xp = x + (size_t)bglob * Sc * Dc + (size_t)s * Dc
                                + half * 128 + quad * 8;
                float Xv[32];
#pragma unroll
                for (int i = 0; i < 8; ++i)
                    *(float4*)&Xv[4 * i] = *(const float4*)(xp + (i >> 1) * 32 + (i & 1) * 4);
#pragma unroll
                for (int i = 0; i < 4; ++i) {
                    short8 Bv;
#pragma unroll
                    for (int j = 0; j < 8; ++j) Bv[j] = bf16_rne(Xv[i * 8 + j]);
                    short8 A = *(const short8*)&Wl[wrowb + half * 128 + i * 32 + quad * 8];
                    acc = __builtin_amdgcn_mfma_f32_16x16x32_bf16(A, Bv, acc, 0, 0, 0);
                }
            }
            if (w == 0) {
                wait32(f0b, (u32)s, lane);                     // h1[s-1] ready (this bg)
                wait32(f1b, (u32)(s >= 3 ? s - 2 : 0), lane);  // WAR: L1 done with h1[s-3]
            }
            __syncthreads();
            mfma_h(256 + half * 256, half * 256, 8, h1b + (size_t)mR * HQ);
        } else {
            if (w == 0) wait32(f1b, (u32)s, lane);             // h2[s-1] ready (this bg)
            __syncthreads();
            mfma_h(512 + half * 256, half * 256, 8, h2b + (size_t)((s + 1) & 1) * HQ);
            if (w == 0) wait32(f0b, (u32)(s + 1), lane);       // h1[s] ready (L0 runs ahead)
            __syncthreads();
            mfma_h(half * 256, half * 256, 8, h1b + (size_t)mW * HQ);
        }

        // park C tile: lane holds D[m=quad*4+reg][n=c16] for gate g, K-half
        *(float4*)&red[((half * 4 + g) * 16 + c16) * 20 + quad * 4] =
            make_float4(acc[0], acc[1], acc[2], acc[3]);
        __syncthreads();

        if (tid < 128) {
            float hv[2];
#pragma unroll
            for (int jj2 = 0; jj2 < 2; ++jj2) {
                const int jl = 2 * jp + jj2;
                float gv[4];
#pragma unroll
                for (int gg = 0; gg < 4; ++gg)
                    gv[gg] = red[((0 + gg) * 16 + bl) * 20 + jl]
                           + red[((4 + gg) * 16 + bl) * 20 + jl] + bias2[jj2][gg];
                const float ig = sigmoidf_fast(gv[0]);
                const float fg = sigmoidf_fast(gv[1]);
                const float gt = tanhf_fast(gv[2]);
                const float og = sigmoidf_fast(gv[3]);
                cst[jj2] = fg * cst[jj2] + ig * gt;
                hv[jj2] = og * tanhf_fast(cst[jj2]);
            }
            u64* hb = isL1 ? (h2b + (size_t)(s & 1) * HQ)
                           : (h1b + (size_t)mW * HQ);
            cstore4((u32*)hb + hsoff, pack2_rne(hv[0], hv[1]));
        }
        __syncthreads();   // drains h stores (vmcnt(0)) before publish
        if (tid == 0)
            __hip_atomic_store(myflag, (u32)(s + 1), __ATOMIC_RELAXED, __HIP_MEMORY_SCOPE_AGENT);
    }

    // ---- FC epilogue: WG b in [0,64) ----
    if (wg < Bc) {
        if (w == 0) wait128(flags1, (u32)Sc, lane);
        __syncthreads();
        const int b = wg;
        const u64* h2 = h2b + (size_t)((Sc - 1) & 1) * HQ;
        const int o = tid & 127, q = tid >> 7;
        const float* wrow = fcw + (size_t)o * Hc;
        float a = 0.0f;
        for (int k4 = q * 32; k4 < q * 32 + 32; ++k4) {
            const float4 f = unpack4(cload8(h2 + (size_t)k4 * 64 + b));
            const float* wr = wrow + 4 * k4;
            a += f.x * wr[0] + f.y * wr[1] + f.z * wr[2] + f.w * wr[3];
        }
        __syncthreads();
        red[q * 128 + o] = a;
        __syncthreads();
        if (tid < OUTc)
            out[b * OUTc + tid] = red[tid] + red[128 + tid] + red[256 + tid] + red[384 + tid] + fcb[tid];
    }
}

extern "C" void kernel_launch(void* const* d_in, const int* in_sizes, int n_in,
                              void* d_out, int out_size, void* d_ws, size_t ws_size,
                              hipStream_t stream) {
    const float* x    = (const float*)d_in[0];
    const float* Wih0 = (const float*)d_in[1];
    const float* Whh0 = (const float*)d_in[2];
    const float* bih0 = (const float*)d_in[3];
    const float* bhh0 = (const float*)d_in[4];
    const float* Wih1 = (const float*)d_in[5];
    const float* Whh1 = (const float*)d_in[6];
    const float* bih1 = (const float*)d_in[7];
    const float* bhh1 = (const float*)d_in[8];
    const float* fcw  = (const float*)d_in[9];
    const float* fcb  = (const float*)d_in[10];
    float* out = (float*)d_out;
    float* wsf = (float*)d_ws;

    hipMemsetAsync(d_ws, 0, WS_BYTES, stream);   // flags=0, h[-1]=0 (bf16 zero bits)

    lstm_persist<<<dim3(NWG), dim3(NTHR), 0, stream>>>(
        x, Wih0, Whh0, bih0, bhh0, Wih1, Whh1, bih1, bhh1, fcw, fcb, out, wsf);
}

// Round 10
// 2037.110 us; speedup vs baseline: 15.6554x; 1.0620x over previous
//
#include <hip/hip_runtime.h>

typedef unsigned long long u64;
typedef unsigned int u32;
typedef __attribute__((ext_vector_type(8))) short short8;   // bf16x8 MFMA frag
typedef __attribute__((ext_vector_type(4))) float floatx4;  // f32x4 MFMA acc

// Problem constants
#define Bc   64
#define Sc   512
#define Dc   256
#define Hc   512
#define OUTc 128

// Kernel config: WG = (row-group rg 0..31, batch-group bg 0..3) per layer.
// WG owns 64 weight rows (4 gates x 16 j) x 16 batches. 8 waves = (gate g, K-half).
#define NWG  256
#define NTHR 512
#define NL0  128
#define JPW  16     // j indices per WG
#define NRW  64     // weight rows per WG
#define KPB  1032   // bf16 LDS row stride (max K 1024 + 8 pad)

#define HQ   8192   // u64s per h buffer: hu64[k/4][b]
#define WS_BYTES (4096 + 5 * HQ * 8)

// ---- coherent accessors: relaxed agent-scope atomics (sc1) ----
__device__ __forceinline__ u64 cload8(const u64* p) {
    return __hip_atomic_load(p, __ATOMIC_RELAXED, __HIP_MEMORY_SCOPE_AGENT);
}
__device__ __forceinline__ void cstore4(u32* p, u32 v) {
    __hip_atomic_store(p, v, __ATOMIC_RELAXED, __HIP_MEMORY_SCOPE_AGENT);
}

__device__ __forceinline__ short bf16_rne(float f) {
    u32 u = __float_as_uint(f);
    u += 0x7fffu + ((u >> 16) & 1u);
    return (short)(u >> 16);
}
__device__ __forceinline__ float4 unpack4(u64 v) {   // FC epilogue only
    u32 lo = (u32)v, hi = (u32)(v >> 32);
    float4 f;
    f.x = __uint_as_float(lo << 16);
    f.y = __uint_as_float(lo & 0xffff0000u);
    f.z = __uint_as_float(hi << 16);
    f.w = __uint_as_float(hi & 0xffff0000u);
    return f;
}
__device__ __forceinline__ u32 pack2_rne(float a, float b) {
    u32 ua = __float_as_uint(a), ub = __float_as_uint(b);
    ua += 0x7fffu + ((ua >> 16) & 1u);
    ub += 0x7fffu + ((ub >> 16) & 1u);
    return (ua >> 16) | (ub & 0xffff0000u);
}
__device__ __forceinline__ short8 frag2(u64 a, u64 b) {
    union { u64 u[2]; short8 s; } c; c.u[0] = a; c.u[1] = b; return c.s;
}

// poll 32 same-bg producer flags: one 128B MALL line per load. wave0 only.
__device__ __forceinline__ void wait32(const u32* fbase, u32 target, int lane) {
    const u32* p = fbase + (lane & 31);
    for (;;) {
        u32 f = __hip_atomic_load(p, __ATOMIC_RELAXED, __HIP_MEMORY_SCOPE_AGENT);
        if (__all(f >= target)) return;
        __builtin_amdgcn_s_sleep(1);
    }
}
// combined two-condition wait: single poll loop, 2 MALL lines
__device__ __forceinline__ void wait2(const u32* fa, u32 ta, const u32* fb, u32 tb, int lane) {
    const u32* pa = fa + (lane & 31);
    const u32* pb = fb + (lane & 31);
    for (;;) {
        u32 va = __hip_atomic_load(pa, __ATOMIC_RELAXED, __HIP_MEMORY_SCOPE_AGENT);
        u32 vb = __hip_atomic_load(pb, __ATOMIC_RELAXED, __HIP_MEMORY_SCOPE_AGENT);
        if (__all((va >= ta) && (vb >= tb))) return;
        __builtin_amdgcn_s_sleep(1);
    }
}
__device__ __forceinline__ void wait128(const u32* flags, u32 target, int lane) {
    const u32* p0 = flags + lane; const u32* p1 = flags + lane + 64;
    for (;;) {
        u32 f0 = __hip_atomic_load(p0, __ATOMIC_RELAXED, __HIP_MEMORY_SCOPE_AGENT);
        u32 f1 = __hip_atomic_load(p1, __ATOMIC_RELAXED, __HIP_MEMORY_SCOPE_AGENT);
        if (__all((f0 >= target) && (f1 >= target))) return;
        __builtin_amdgcn_s_sleep(1);
    }
}

__device__ __forceinline__ float sigmoidf_fast(float v) {
    return 1.0f / (1.0f + __expf(-v));
}
__device__ __forceinline__ float tanhf_fast(float v) {
    return 2.0f / (1.0f + __expf(-2.0f * v)) - 1.0f;
}

extern "C" __global__ void __launch_bounds__(NTHR)
lstm_persist(const float* __restrict__ x,
             const float* __restrict__ Wih0, const float* __restrict__ Whh0,
             const float* __restrict__ bih0, const float* __restrict__ bhh0,
             const float* __restrict__ Wih1, const float* __restrict__ Whh1,
             const float* __restrict__ bih1, const float* __restrict__ bhh1,
             const float* __restrict__ fcw, const float* __restrict__ fcb,
             float* __restrict__ out, float* __restrict__ wsf)
{
    __shared__ short Wl[NRW * KPB];          // 132 KB bf16 weights, resident
    __shared__ float red[2 * 4 * 16 * 20];   // 10.2 KB: [half][gate][b16][jl pad20]

    u32* flags0 = (u32*)wsf;                 // [4 bg][32 rg]
    u32* flags1 = flags0 + 128;
    u64* h1b = (u64*)((char*)wsf + 4096);    // [3][HQ]
    u64* h2b = h1b + 3 * HQ;                 // [2][HQ]

    const int wg  = blockIdx.x;
    const int tid = threadIdx.x;
    const bool isL1 = (wg >= NL0);
    const int wgl = isL1 ? wg - NL0 : wg;
    const int rg = wgl >> 2, bg = wgl & 3;
    const int j0 = rg * JPW;
    const int K  = isL1 ? 1024 : 768;
    const int KD = isL1 ? 512  : 256;

    // ---- one-time weight staging: 64 rows (g*16+jl) x K, fp32 -> bf16 ----
    {
        const float* Wi = isL1 ? Wih1 : Wih0;
        const float* Wh = isL1 ? Whh1 : Whh0;
        for (int r = 0; r < NRW; ++r) {
            const int row = (r >> 4) * Hc + j0 + (r & 15);
            for (int c = tid; c < K; c += NTHR) {
                float v = (c < KD) ? Wi[(size_t)row * KD + c] : Wh[(size_t)row * Hc + (c - KD)];
                Wl[r * KPB + c] = bf16_rne(v);
            }
        }
    }
    __syncthreads();

    // ---- wave mapping: w = (gate g)*2 + K-half ----
    const int w    = tid >> 6;
    const int lane = tid & 63;
    const int g    = w >> 1;
    const int half = w & 1;
    const int quad = lane >> 4;
    const int c16  = lane & 15;
    const int bglob = bg * 16 + c16;                    // B-frag batch (n = lane&15)
    const int wrowb = (g * 16 + c16) * KPB;             // A-frag row (m = lane&15)

    // ---- cell mapping: tid<128 -> (bl = tid&15, jp = tid>>4), 2 cells (j pair) ----
    const int bl = tid & 15, jp = tid >> 4;
    float cst[2] = {0.0f, 0.0f};
    float bias2[2][4];
    {
        const float* bi = isL1 ? bih1 : bih0;
        const float* bh = isL1 ? bhh1 : bhh0;
#pragma unroll
        for (int jj2 = 0; jj2 < 2; ++jj2) {
            const int j = j0 + 2 * jp + jj2;
#pragma unroll
            for (int gg = 0; gg < 4; ++gg)
                bias2[jj2][gg] = bi[gg * Hc + j] + bh[gg * Hc + j];
        }
    }
    const int hsoff = ((j0 + 2 * jp) >> 2) * 128 + 2 * (bg * 16 + bl) + (jp & 1);

    u32* myflag = (isL1 ? flags1 : flags0) + bg * 32 + rg;
    const u32* f0b = flags0 + bg * 32;
    const u32* f1b = flags1 + bg * 32;

    for (int s = 0; s < Sc; ++s) {
        floatx4 acc = {0.0f, 0.0f, 0.0f, 0.0f};

        const int mW = s % 3;            // h1[s] slot (L0 write, L1 read)
        const int mR = (s + 2) % 3;      // h1[s-1] slot (L0 recurrent read)

        if (!isL1) {
            // x-phase: dependency-free; fp32 x -> bf16 B-frag on the fly.
            // Runs before the wait: overlaps producer stragglers.
            {
                const float* xp = x + (size_t)bglob * Sc * Dc + (size_t)s * Dc
                                + half * 128 + quad * 8;
                float Xv[32];
#pragma unroll
                for (int i = 0; i < 8; ++i)
                    *(float4*)&Xv[4 * i] = *(const float4*)(xp + (i >> 1) * 32 + (i & 1) * 4);
#pragma unroll
                for (int i = 0; i < 4; ++i) {
                    short8 Bv;
#pragma unroll
                    for (int j = 0; j < 8; ++j) Bv[j] = bf16_rne(Xv[i * 8 + j]);
                    short8 A = *(const short8*)&Wl[wrowb + half * 128 + i * 32 + quad * 8];
                    acc = __builtin_amdgcn_mfma_f32_16x16x32_bf16(A, Bv, acc, 0, 0, 0);
                }
            }
            // single combined wait: h1[s-1] ready AND L1 done with h1[s-3] (WAR)
            if (w == 0) wait2(f0b, (u32)s, f1b, (u32)(s >= 3 ? s - 2 : 0), lane);
            __syncthreads();
            // recurrent phase: all 16 sc1 loads up-front, then ds_read+MFMA
            {
                const u64* hb_ = h1b + (size_t)mR * HQ;
                u64 F[16];
#pragma unroll
                for (int i = 0; i < 8; ++i) {
                    const int q8 = (half * 64) + i * 8 + quad * 2;
                    F[2 * i]     = cload8(hb_ + (size_t)q8 * 64 + bglob);
                    F[2 * i + 1] = cload8(hb_ + (size_t)(q8 + 1) * 64 + bglob);
                }
#pragma unroll
                for (int i = 0; i < 8; ++i) {
                    short8 A = *(const short8*)&Wl[wrowb + 256 + half * 256 + i * 32 + quad * 8];
                    acc = __builtin_amdgcn_mfma_f32_16x16x32_bf16(A, frag2(F[2 * i], F[2 * i + 1]), acc, 0, 0, 0);
                }
            }
        } else {
            // L1: ONE combined wait (L0 runs 1-2 ahead via triple buffer), then
            // both phases' 32 sc1 loads issued together, then 32 MFMAs.
            if (w == 0) wait2(f1b, (u32)s, f0b, (u32)(s + 1), lane);
            __syncthreads();
            {
                const u64* hb2 = h2b + (size_t)((s + 1) & 1) * HQ;   // h2[s-1]
                const u64* hb1 = h1b + (size_t)mW * HQ;              // h1[s]
                u64 F[32];
#pragma unroll
                for (int i = 0; i < 8; ++i) {
                    const int q8 = (half * 64) + i * 8 + quad * 2;
                    F[2 * i]     = cload8(hb2 + (size_t)q8 * 64 + bglob);
                    F[2 * i + 1] = cload8(hb2 + (size_t)(q8 + 1) * 64 + bglob);
                }
#pragma unroll
                for (int i = 0; i < 8; ++i) {
                    const int q8 = (half * 64) + i * 8 + quad * 2;
                    F[16 + 2 * i] = cload8(hb1 + (size_t)q8 * 64 + bglob);
                    F[17 + 2 * i] = cload8(hb1 + (size_t)(q8 + 1) * 64 + bglob);
                }
#pragma unroll
                for (int i = 0; i < 8; ++i) {   // own-recurrent: W cols 512+half*256
                    short8 A = *(const short8*)&Wl[wrowb + 512 + half * 256 + i * 32 + quad * 8];
                    acc = __builtin_amdgcn_mfma_f32_16x16x32_bf16(A, frag2(F[2 * i], F[2 * i + 1]), acc, 0, 0, 0);
                }
#pragma unroll
                for (int i = 0; i < 8; ++i) {   // input part: W cols half*256
                    short8 A = *(const short8*)&Wl[wrowb + half * 256 + i * 32 + quad * 8];
                    acc = __builtin_amdgcn_mfma_f32_16x16x32_bf16(A, frag2(F[16 + 2 * i], F[17 + 2 * i]), acc, 0, 0, 0);
                }
            }
        }

        // park C tile: lane holds D[m=quad*4+reg][n=c16] for gate g, K-half
        *(float4*)&red[((half * 4 + g) * 16 + c16) * 20 + quad * 4] =
            make_float4(acc[0], acc[1], acc[2], acc[3]);
        __syncthreads();

        if (tid < 128) {
            float hv[2];
#pragma unroll
            for (int jj2 = 0; jj2 < 2; ++jj2) {
                const int jl = 2 * jp + jj2;
                float gv[4];
#pragma unroll
                for (int gg = 0; gg < 4; ++gg)
                    gv[gg] = red[((0 + gg) * 16 + bl) * 20 + jl]
                           + red[((4 + gg) * 16 + bl) * 20 + jl] + bias2[jj2][gg];
                const float ig = sigmoidf_fast(gv[0]);
                const float fg = sigmoidf_fast(gv[1]);
                const float gt = tanhf_fast(gv[2]);
                const float og = sigmoidf_fast(gv[3]);
                cst[jj2] = fg * cst[jj2] + ig * gt;
                hv[jj2] = og * tanhf_fast(cst[jj2]);
            }
            u64* hb = isL1 ? (h2b + (size_t)(s & 1) * HQ)
                           : (h1b + (size_t)mW * HQ);
            cstore4((u32*)hb + hsoff, pack2_rne(hv[0], hv[1]));
        }
        __syncthreads();   // drains h stores (vmcnt(0)) before publish
        if (tid == 0)
            __hip_atomic_store(myflag, (u32)(s + 1), __ATOMIC_RELAXED, __HIP_MEMORY_SCOPE_AGENT);
    }

    // ---- FC epilogue: WG b in [0,64) ----
    if (wg < Bc) {
        if (w == 0) wait128(flags1, (u32)Sc, lane);
        __syncthreads();
        const int b = wg;
        const u64* h2 = h2b + (size_t)((Sc - 1) & 1) * HQ;
        const int o = tid & 127, q = tid >> 7;
        const float* wrow = fcw + (size_t)o * Hc;
        float a = 0.0f;
        for (int k4 = q * 32; k4 < q * 32 + 32; ++k4) {
            const float4 f = unpack4(cload8(h2 + (size_t)k4 * 64 + b));
            const float* wr = wrow + 4 * k4;
            a += f.x * wr[0] + f.y * wr[1] + f.z * wr[2] + f.w * wr[3];
        }
        __syncthreads();
        red[q * 128 + o] = a;
        __syncthreads();
        if (tid < OUTc)
            out[b * OUTc + tid] = red[tid] + red[128 + tid] + red[256 + tid] + red[384 + tid] + fcb[tid];
    }
}

extern "C" void kernel_launch(void* const* d_in, const int* in_sizes, int n_in,
                              void* d_out, int out_size, void* d_ws, size_t ws_size,
                              hipStream_t stream) {
    const float* x    = (const float*)d_in[0];
    const float* Wih0 = (const float*)d_in[1];
    const float* Whh0 = (const float*)d_in[2];
    const float* bih0 = (const float*)d_in[3];
    const float* bhh0 = (const float*)d_in[4];
    const float* Wih1 = (const float*)d_in[5];
    const float* Whh1 = (const float*)d_in[6];
    const float* bih1 = (const float*)d_in[7];
    const float* bhh1 = (const float*)d_in[8];
    const float* fcw  = (const float*)d_in[9];
    const float* fcb  = (const float*)d_in[10];
    float* out = (float*)d_out;
    float* wsf = (float*)d_ws;

    hipMemsetAsync(d_ws, 0, WS_BYTES, stream);   // flags=0, h[-1]=0 (bf16 zero bits)

    lstm_persist<<<dim3(NWG), dim3(NTHR), 0, stream>>>(
        x, Wih0, Whh0, bih0, bhh0, Wih1, Whh1, bih1, bhh1, fcw, fcb, out, wsf);
}